// Round 1
// baseline (4103.136 us; speedup 1.0000x reference)
//
#include <hip/hip_runtime.h>

typedef unsigned short u16;
typedef unsigned int u32;
typedef __attribute__((ext_vector_type(8))) short bf16x8;   // 8 bf16 in 4 VGPRs (guide §3)
typedef __attribute__((ext_vector_type(4))) float f32x4;

__device__ __forceinline__ u16 f2bf(float v) {  // RNE f32 -> bf16
  u32 x = __builtin_bit_cast(u32, v);
  x += 0x7FFFu + ((x >> 16) & 1u);
  return (u16)(x >> 16);
}

// block = 256 threads (4 waves): wave shfl reduce then LDS combine
__device__ __forceinline__ float block_sum(float v, float* buf) {
#pragma unroll
  for (int m = 32; m >= 1; m >>= 1) v += __shfl_xor(v, m);
  int w = threadIdx.x >> 6;
  if ((threadIdx.x & 63) == 0) buf[w] = v;
  __syncthreads();
  v = buf[0] + buf[1] + buf[2] + buf[3];
  __syncthreads();
  return v;
}

__global__ __launch_bounds__(256) void keybias_kernel(const float* __restrict__ mask,
                                                      float* __restrict__ kb, int n) {
  int i = blockIdx.x * 256 + threadIdx.x;
  if (i < n) kb[i] = (1.0f - mask[i]) * -10000.0f;
}

// one block per token: emb gather + LayerNorm + gaussian-noise injection
__global__ __launch_bounds__(256)
void embed_ln_kernel(const int* __restrict__ ids, const int* __restrict__ tts,
                     const float* __restrict__ imp, const float* __restrict__ noise,
                     const float* __restrict__ wemb, const float* __restrict__ pemb,
                     const float* __restrict__ temb, const float* __restrict__ g,
                     const float* __restrict__ bb, float* __restrict__ x,
                     u16* __restrict__ xb) {
  __shared__ float buf[4];
  long t = blockIdx.x;
  int s = (int)(t & 511);
  int tid = threadIdx.x;
  long id = ids[t], tt = tts[t];
  float e[3];
#pragma unroll
  for (int i = 0; i < 3; ++i) {
    int d = tid + i * 256;
    e[i] = wemb[id * 768 + d] + pemb[(long)s * 768 + d] + temb[tt * 768 + d];
  }
  float mu = block_sum(e[0] + e[1] + e[2], buf) * (1.0f / 768.0f);
  float vs = 0.f;
#pragma unroll
  for (int i = 0; i < 3; ++i) { float dd = e[i] - mu; vs += dd * dd; }
  float inv = rsqrtf(block_sum(vs, buf) * (1.0f / 768.0f) + 1e-12f);
  float ip = imp[t];
  float sig = 1.0f - ip;
  bool app = (ip != 0.0f);  // uniform per block
#pragma unroll
  for (int i = 0; i < 3; ++i) {
    int d = tid + i * 256;
    float y = (e[i] - mu) * inv * g[d] + bb[d];
    if (app) y = y * (1.0f + noise[t * 768 + d] * sig);  // emb + noise*sigma*emb
    x[t * 768 + d] = y;
    xb[t * 768 + d] = f2bf(y);
  }
}

// residual + LayerNorm; writes f32 stream + bf16 GEMM operand
__global__ __launch_bounds__(256)
void ln_res_kernel(const float* __restrict__ xin, const float* __restrict__ yin,
                   const float* __restrict__ g, const float* __restrict__ bb,
                   float* __restrict__ xout, u16* __restrict__ xbout) {
  __shared__ float buf[4];
  long t = blockIdx.x;
  int tid = threadIdx.x;
  float e[3];
#pragma unroll
  for (int i = 0; i < 3; ++i) {
    int d = tid + i * 256;
    e[i] = xin[t * 768 + d] + yin[t * 768 + d];
  }
  float mu = block_sum(e[0] + e[1] + e[2], buf) * (1.0f / 768.0f);
  float vs = 0.f;
#pragma unroll
  for (int i = 0; i < 3; ++i) { float dd = e[i] - mu; vs += dd * dd; }
  float inv = rsqrtf(block_sum(vs, buf) * (1.0f / 768.0f) + 1e-12f);
#pragma unroll
  for (int i = 0; i < 3; ++i) {
    int d = tid + i * 256;
    float v = (e[i] - mu) * inv * g[d] + bb[d];
    xout[t * 768 + d] = v;
    xbout[t * 768 + d] = f2bf(v);
  }
}

// convert+transpose one layer's 6 weight matrices f32 (K x N) -> bf16 (N x K)
// flat tile id: [0,2304) qkvo (768x768), [2304,4608) Wi (768x3072), [4608,6912) Wd (3072x768)
__global__ __launch_bounds__(256)
void convert_w_kernel(const float* __restrict__ wq, const float* __restrict__ wk,
                      const float* __restrict__ wv, const float* __restrict__ wo,
                      const float* __restrict__ wi, const float* __restrict__ wd,
                      u16* __restrict__ wqkvob, u16* __restrict__ wib,
                      u16* __restrict__ wdb) {
  __shared__ float tile[32][33];
  int t = blockIdx.x;
  const float* in;
  u16* outp;
  int Kd, Nd, kt, nt;
  if (t < 2304) {
    int m = t / 576, lt = t % 576;
    in = (m == 0) ? wq : (m == 1) ? wk : (m == 2) ? wv : wo;
    outp = wqkvob + (long)m * 589824;
    Kd = 768; Nd = 768; kt = lt / 24; nt = lt % 24;
  } else if (t < 4608) {
    int lt = t - 2304;
    in = wi; outp = wib; Kd = 768; Nd = 3072; kt = lt / 96; nt = lt % 96;
  } else {
    int lt = t - 4608;
    in = wd; outp = wdb; Kd = 3072; Nd = 768; kt = lt / 24; nt = lt % 24;
  }
  int tx = threadIdx.x, ty = threadIdx.y;
#pragma unroll
  for (int i = 0; i < 4; ++i)
    tile[ty + i * 8][tx] = in[(long)(kt * 32 + ty + i * 8) * Nd + nt * 32 + tx];
  __syncthreads();
#pragma unroll
  for (int i = 0; i < 4; ++i)
    outp[(long)(nt * 32 + ty + i * 8) * Kd + kt * 32 + tx] = f2bf(tile[tx][ty + i * 8]);
}

// V (B,S,NH*64) bf16 -> Vt (B,NH,64,S) bf16 so attention can ds_read_b128 V-fragments
__global__ __launch_bounds__(256)
void transpose_v_kernel(const u16* __restrict__ vb, u16* __restrict__ vtb) {
  __shared__ u16 tile[32][33];
  int s0 = blockIdx.x * 32, d0 = blockIdx.y * 32;
  int b = blockIdx.z / 12, h = blockIdx.z % 12;
  int tx = threadIdx.x, ty = threadIdx.y;
#pragma unroll
  for (int i = 0; i < 4; ++i)
    tile[ty + i * 8][tx] = vb[(long)(b * 512 + s0 + ty + i * 8) * 768 + h * 64 + d0 + tx];
  __syncthreads();
#pragma unroll
  for (int i = 0; i < 4; ++i)
    vtb[(long)((b * 12 + h) * 64 + d0 + ty + i * 8) * 512 + s0 + tx] = tile[tx][ty + i * 8];
}

// C = A (M x K, bf16 rowmajor) * B^T (B is N x K bf16 rowmajor) + bias[n]
// 128x128 tile, BK=32, 4 waves each 64x64 via 4x4 mfma_f32_16x16x32_bf16
// EPI: 1 = +bias, 2 = gelu(+bias).  OBF16: output dtype.
// gridDim.z selects B matrix slab (QKV batching): B += z*strideB, Out += z*strideOut
template <int EPI, bool OBF16>
__global__ __launch_bounds__(256)
void gemm_kernel(const u16* __restrict__ A, const u16* __restrict__ Bmat, long strideB,
                 const float* __restrict__ bias0, const float* __restrict__ bias1,
                 const float* __restrict__ bias2, void* __restrict__ Out, long strideOut,
                 int M, int N, int K) {
  __shared__ __align__(16) u16 As[128][40];  // +8 pad: 16B-aligned rows, 2-way-max banks
  __shared__ __align__(16) u16 Bs[128][40];
  int z = blockIdx.z;
  const u16* B = Bmat + (long)z * strideB;
  const float* bias = (z == 0) ? bias0 : ((z == 1) ? bias1 : bias2);
  int m0 = blockIdx.x * 128, n0 = blockIdx.y * 128;
  int tid = threadIdx.x;
  int w = tid >> 6, lane = tid & 63;
  int wr = (w >> 1) * 64, wc = (w & 1) * 64;
  int quad = lane >> 4, l16 = lane & 15;
  f32x4 acc[4][4] = {};
  for (int kk = 0; kk < K; kk += 32) {
#pragma unroll
    for (int i = 0; i < 2; ++i) {  // 512 chunks of 8 bf16, 2 per thread
      int c = tid + i * 256;
      int row = c >> 2, kc = c & 3;
      *(uint4*)&As[row][kc * 8] = *(const uint4*)&A[(long)(m0 + row) * K + kk + kc * 8];
      *(uint4*)&Bs[row][kc * 8] = *(const uint4*)&B[(long)(n0 + row) * K + kk + kc * 8];
    }
    __syncthreads();
    bf16x8 af[4], bfv[4];
#pragma unroll
    for (int i = 0; i < 4; ++i) af[i] = *(const bf16x8*)&As[wr + i * 16 + l16][quad * 8];
#pragma unroll
    for (int j = 0; j < 4; ++j) bfv[j] = *(const bf16x8*)&Bs[wc + j * 16 + l16][quad * 8];
#pragma unroll
    for (int i = 0; i < 4; ++i)
#pragma unroll
      for (int j = 0; j < 4; ++j)
        acc[i][j] = __builtin_amdgcn_mfma_f32_16x16x32_bf16(af[i], bfv[j], acc[i][j], 0, 0, 0);
    __syncthreads();
  }
#pragma unroll
  for (int i = 0; i < 4; ++i) {
#pragma unroll
    for (int j = 0; j < 4; ++j) {
      int n = n0 + wc + j * 16 + l16;
      float bv = bias[n];
#pragma unroll
      for (int r = 0; r < 4; ++r) {  // C/D: row=(lane>>4)*4+reg, col=lane&15 (m89)
        int m = m0 + wr + i * 16 + quad * 4 + r;
        float v = acc[i][j][r] + bv;
        if (EPI == 2) v = v * 0.5f * (1.0f + erff(v * 0.70710678118654752f));
        long idx = (long)z * strideOut + (long)m * N + n;
        if (OBF16) ((u16*)Out)[idx] = f2bf(v);
        else ((float*)Out)[idx] = v;
      }
    }
  }
}

// fused flash attention: block = (b,h,64-q-rows); wave w owns 16 q rows.
// online softmax in MFMA C-layout; P -> per-wave LDS -> A-operand layout (m120 pattern)
__global__ __launch_bounds__(256)
void attn_kernel(const u16* __restrict__ qb, const u16* __restrict__ kb,
                 const u16* __restrict__ vtb, const float* __restrict__ keybias,
                 u16* __restrict__ ctxb) {
  __shared__ __align__(16) u16 Ks[64][72];   // [key][d]
  __shared__ __align__(16) u16 Vts[64][72];  // [d][key]
  __shared__ __align__(16) u16 Ps[4][16][72];
  int qt = blockIdx.x, h = blockIdx.y, b = blockIdx.z;
  int tid = threadIdx.x, w = tid >> 6, lane = tid & 63;
  int quad = lane >> 4, l16 = lane & 15;
  long qrow = (long)(b * 512 + qt * 64 + w * 16 + l16);
  bf16x8 qf0 = *(const bf16x8*)&qb[qrow * 768 + h * 64 + quad * 8];
  bf16x8 qf1 = *(const bf16x8*)&qb[qrow * 768 + h * 64 + 32 + quad * 8];
  f32x4 accO[4] = {};
  float mi[4], li[4];
#pragma unroll
  for (int r = 0; r < 4; ++r) { mi[r] = -1e30f; li[r] = 0.f; }
  for (int kt = 0; kt < 8; ++kt) {
    __syncthreads();
#pragma unroll
    for (int i = 0; i < 2; ++i) {
      int c = tid + i * 256;
      int row = c >> 3, dc = c & 7;
      *(uint4*)&Ks[row][dc * 8] =
          *(const uint4*)&kb[(long)(b * 512 + kt * 64 + row) * 768 + h * 64 + dc * 8];
      *(uint4*)&Vts[row][dc * 8] =
          *(const uint4*)&vtb[(long)((b * 12 + h) * 64 + row) * 512 + kt * 64 + dc * 8];
    }
    __syncthreads();
    f32x4 s[4] = {};
#pragma unroll
    for (int j = 0; j < 4; ++j) {
      bf16x8 kf0 = *(const bf16x8*)&Ks[j * 16 + l16][quad * 8];
      s[j] = __builtin_amdgcn_mfma_f32_16x16x32_bf16(qf0, kf0, s[j], 0, 0, 0);
      bf16x8 kf1 = *(const bf16x8*)&Ks[j * 16 + l16][32 + quad * 8];
      s[j] = __builtin_amdgcn_mfma_f32_16x16x32_bf16(qf1, kf1, s[j], 0, 0, 0);
    }
#pragma unroll
    for (int j = 0; j < 4; ++j) {
      float kbv = keybias[b * 512 + kt * 64 + j * 16 + l16];
#pragma unroll
      for (int r = 0; r < 4; ++r) s[j][r] = s[j][r] * 0.125f + kbv;
    }
#pragma unroll
    for (int r = 0; r < 4; ++r) {  // row lives in 16 lanes sharing (lane>>4)
      float mx = fmaxf(fmaxf(s[0][r], s[1][r]), fmaxf(s[2][r], s[3][r]));
      mx = fmaxf(mx, __shfl_xor(mx, 1));
      mx = fmaxf(mx, __shfl_xor(mx, 2));
      mx = fmaxf(mx, __shfl_xor(mx, 4));
      mx = fmaxf(mx, __shfl_xor(mx, 8));
      float mn = fmaxf(mi[r], mx);
      float alpha = __expf(mi[r] - mn);
      float ps = 0.f;
#pragma unroll
      for (int j = 0; j < 4; ++j) { s[j][r] = __expf(s[j][r] - mn); ps += s[j][r]; }
      ps += __shfl_xor(ps, 1);
      ps += __shfl_xor(ps, 2);
      ps += __shfl_xor(ps, 4);
      ps += __shfl_xor(ps, 8);
      li[r] = li[r] * alpha + ps;
      mi[r] = mn;
#pragma unroll
      for (int j = 0; j < 4; ++j) accO[j][r] *= alpha;
    }
#pragma unroll
    for (int j = 0; j < 4; ++j)
#pragma unroll
      for (int r = 0; r < 4; ++r)
        Ps[w][quad * 4 + r][j * 16 + l16] = f2bf(s[j][r]);
    __syncthreads();  // orders Ps write -> Ps read (uniform across waves)
#pragma unroll
    for (int kk = 0; kk < 2; ++kk) {
      bf16x8 pf = *(const bf16x8*)&Ps[w][l16][kk * 32 + quad * 8];
#pragma unroll
      for (int j = 0; j < 4; ++j) {
        bf16x8 vf = *(const bf16x8*)&Vts[j * 16 + l16][kk * 32 + quad * 8];
        accO[j] = __builtin_amdgcn_mfma_f32_16x16x32_bf16(pf, vf, accO[j], 0, 0, 0);
      }
    }
  }
#pragma unroll
  for (int j = 0; j < 4; ++j)
#pragma unroll
    for (int r = 0; r < 4; ++r) {
      float v = accO[j][r] / li[r];
      long row = (long)(b * 512 + qt * 64 + w * 16 + quad * 4 + r);
      ctxb[row * 768 + h * 64 + j * 16 + l16] = f2bf(v);
    }
}

__global__ __launch_bounds__(256)
void pooler_kernel(const float* __restrict__ xfin, const float* __restrict__ pw,
                   const float* __restrict__ pb, float* __restrict__ outp) {
  __shared__ float xr[768];
  int o = blockIdx.x * 256 + threadIdx.x;
  int b = blockIdx.y;
  for (int i = threadIdx.x; i < 768; i += 256) xr[i] = xfin[(long)b * 512 * 768 + i];
  __syncthreads();
  float acc = pb[o];
  for (int k = 0; k < 768; ++k) acc += xr[k] * pw[(long)k * 768 + o];
  outp[(long)b * 768 + o] = tanhf(acc);
}

extern "C" void kernel_launch(void* const* d_in, const int* in_sizes, int n_in,
                              void* d_out, int out_size, void* d_ws, size_t ws_size,
                              hipStream_t stream) {
  const int* ids = (const int*)d_in[0];
  const int* tts = (const int*)d_in[1];
  const float* amask = (const float*)d_in[2];
  const float* imp = (const float*)d_in[3];
  const float* noise = (const float*)d_in[4];
  const float* wemb = (const float*)d_in[5];
  const float* pemb = (const float*)d_in[6];
  const float* temb = (const float*)d_in[7];
  const float* elng = (const float*)d_in[8];
  const float* elnb = (const float*)d_in[9];
  const float* Wq = (const float*)d_in[10];
  const float* bq = (const float*)d_in[11];
  const float* Wk = (const float*)d_in[12];
  const float* bk = (const float*)d_in[13];
  const float* Wv = (const float*)d_in[14];
  const float* bv = (const float*)d_in[15];
  const float* Wo = (const float*)d_in[16];
  const float* bo = (const float*)d_in[17];
  const float* ln1g = (const float*)d_in[18];
  const float* ln1b = (const float*)d_in[19];
  const float* Wi = (const float*)d_in[20];
  const float* bi = (const float*)d_in[21];
  const float* Wd = (const float*)d_in[22];
  const float* bd = (const float*)d_in[23];
  const float* ln2g = (const float*)d_in[24];
  const float* ln2b = (const float*)d_in[25];
  const float* poolw = (const float*)d_in[26];
  const float* poolb = (const float*)d_in[27];
  float* out = (float*)d_out;

  const long T = 8192;  // B*S
  char* p = (char*)d_ws;
  auto carve = [&](size_t bytes) -> void* {
    void* r = (void*)p;
    p += (bytes + 255) & ~(size_t)255;
    return r;
  };
  float* x = (float*)carve(T * 768 * 4);
  float* y = (float*)carve(T * 768 * 4);
  u16* xb = (u16*)carve(T * 768 * 2);
  u16* qkvb = (u16*)carve(3 * T * 768 * 2);
  u16* vtb = (u16*)carve(T * 768 * 2);
  u16* ctxb = (u16*)carve(T * 768 * 2);
  u16* hb = (u16*)carve(T * 3072 * 2);
  u16* wqkvob = (u16*)carve(4L * 589824 * 2);
  u16* wib = (u16*)carve(2359296L * 2);
  u16* wdb = (u16*)carve(2359296L * 2);
  float* kbias = (float*)carve(T * 4);
  if ((size_t)(p - (char*)d_ws) > ws_size) return;  // ws too small: fail visibly

  keybias_kernel<<<(int)(T / 256), 256, 0, stream>>>(amask, kbias, (int)T);
  embed_ln_kernel<<<(int)T, 256, 0, stream>>>(ids, tts, imp, noise, wemb, pemb, temb,
                                              elng, elnb, x, xb);

  for (int l = 0; l < 12; ++l) {
    convert_w_kernel<<<6912, dim3(32, 8), 0, stream>>>(
        Wq + (long)l * 589824, Wk + (long)l * 589824, Wv + (long)l * 589824,
        Wo + (long)l * 589824, Wi + (long)l * 2359296, Wd + (long)l * 2359296,
        wqkvob, wib, wdb);
    // QKV batched over z
    gemm_kernel<1, true><<<dim3(64, 6, 3), 256, 0, stream>>>(
        xb, wqkvob, 589824L, bq + (long)l * 768, bk + (long)l * 768, bv + (long)l * 768,
        (void*)qkvb, T * 768, 8192, 768, 768);
    transpose_v_kernel<<<dim3(16, 2, 192), dim3(32, 8), 0, stream>>>(qkvb + 2 * T * 768, vtb);
    attn_kernel<<<dim3(8, 12, 16), 256, 0, stream>>>(qkvb, qkvb + T * 768, vtb, kbias, ctxb);
    gemm_kernel<1, false><<<dim3(64, 6, 1), 256, 0, stream>>>(
        ctxb, wqkvob + 3L * 589824, 0L, bo + (long)l * 768, bo + (long)l * 768,
        bo + (long)l * 768, (void*)y, 0L, 8192, 768, 768);
    ln_res_kernel<<<(int)T, 256, 0, stream>>>(x, y, ln1g + (long)l * 768,
                                              ln1b + (long)l * 768, x, xb);
    gemm_kernel<2, true><<<dim3(64, 24, 1), 256, 0, stream>>>(
        xb, wib, 0L, bi + (long)l * 3072, bi + (long)l * 3072, bi + (long)l * 3072,
        (void*)hb, 0L, 8192, 3072, 768);
    gemm_kernel<1, false><<<dim3(64, 6, 1), 256, 0, stream>>>(
        hb, wdb, 0L, bd + (long)l * 768, bd + (long)l * 768, bd + (long)l * 768,
        (void*)y, 0L, 8192, 768, 3072);
    float* xo = (l == 11) ? out : x;
    ln_res_kernel<<<(int)T, 256, 0, stream>>>(x, y, ln2g + (long)l * 768,
                                              ln2b + (long)l * 768, xo, xb);
  }
  pooler_kernel<<<dim3(3, 16), 256, 0, stream>>>(out, poolw, poolb, out + T * 768);
}

// Round 2
// 3811.214 us; speedup vs baseline: 1.0766x; 1.0766x over previous
//
#include <hip/hip_runtime.h>

typedef unsigned short u16;
typedef unsigned int u32;
typedef __attribute__((ext_vector_type(8))) short bf16x8;   // 8 bf16 in 4 VGPRs
typedef __attribute__((ext_vector_type(4))) float f32x4;
typedef __attribute__((ext_vector_type(4))) unsigned short u16x4;
typedef __attribute__((ext_vector_type(8))) unsigned short u16x8;

__device__ __forceinline__ u16 f2bf(float v) {  // RNE f32 -> bf16
  u32 x = __builtin_bit_cast(u32, v);
  x += 0x7FFFu + ((x >> 16) & 1u);
  return (u16)(x >> 16);
}

__device__ __forceinline__ float wave_sum(float v) {
#pragma unroll
  for (int m = 32; m >= 1; m >>= 1) v += __shfl_xor(v, m);
  return v;
}

// async global->LDS DMA, 16B per lane; LDS dest = wave-uniform base + lane*16 (m104/m108)
__device__ __forceinline__ void gload_lds16(const u16* g, u16* l) {
  __builtin_amdgcn_global_load_lds(
      (const __attribute__((address_space(1))) unsigned int*)g,
      (__attribute__((address_space(3))) unsigned int*)l, 16, 0, 0);
}

__global__ __launch_bounds__(256) void keybias_kernel(const float* __restrict__ mask,
                                                      float* __restrict__ kb, int n) {
  int i = blockIdx.x * 256 + threadIdx.x;
  if (i < n) kb[i] = (1.0f - mask[i]) * -10000.0f;
}

// wave-per-token: emb gather + LayerNorm + gaussian-noise, float4 throughout
__global__ __launch_bounds__(256)
void embed_ln_kernel(const int* __restrict__ ids, const int* __restrict__ tts,
                     const float* __restrict__ imp, const float* __restrict__ noise,
                     const float* __restrict__ wemb, const float* __restrict__ pemb,
                     const float* __restrict__ temb, const float* __restrict__ g,
                     const float* __restrict__ bb, float* __restrict__ x,
                     u16* __restrict__ xb) {
  long t = (long)blockIdx.x * 4 + (threadIdx.x >> 6);
  int lane = threadIdx.x & 63;
  int s = (int)(t & 511);
  long id = ids[t], tt = tts[t];
  f32x4 e[3];
#pragma unroll
  for (int i = 0; i < 3; ++i) {
    int c4 = i * 64 + lane;
    e[i] = *(const f32x4*)&wemb[(id * 192 + c4) * 4] + *(const f32x4*)&pemb[((long)s * 192 + c4) * 4]
         + *(const f32x4*)&temb[(tt * 192 + c4) * 4];
  }
  float sm = 0.f;
#pragma unroll
  for (int i = 0; i < 3; ++i) sm += e[i][0] + e[i][1] + e[i][2] + e[i][3];
  float mu = wave_sum(sm) * (1.0f / 768.0f);
  float vs = 0.f;
#pragma unroll
  for (int i = 0; i < 3; ++i)
#pragma unroll
    for (int c = 0; c < 4; ++c) { float d = e[i][c] - mu; vs += d * d; }
  float inv = rsqrtf(wave_sum(vs) * (1.0f / 768.0f) + 1e-12f);
  float ip = imp[t];
  float sig = 1.0f - ip;
  bool app = (ip != 0.0f);  // uniform per token(wave)
#pragma unroll
  for (int i = 0; i < 3; ++i) {
    int c4 = i * 64 + lane;
    f32x4 gv = *(const f32x4*)&g[c4 * 4], bv = *(const f32x4*)&bb[c4 * 4];
    f32x4 o = (e[i] - mu) * inv * gv + bv;
    if (app) {
      f32x4 nz = *(const f32x4*)&noise[(t * 192 + c4) * 4];
      o = o * (1.0f + nz * sig);
    }
    *(f32x4*)&x[(t * 192 + c4) * 4] = o;
    u16x4 pk;
#pragma unroll
    for (int c = 0; c < 4; ++c) pk[c] = f2bf(o[c]);
    *(u16x4*)&xb[(t * 192 + c4) * 4] = pk;
  }
}

// wave-per-token residual(x + y0 + y1) + LayerNorm; writes f32 stream + bf16 operand
__global__ __launch_bounds__(256)
void ln_res_kernel(const float* __restrict__ xin, const float* __restrict__ y0,
                   const float* __restrict__ y1, const float* __restrict__ g,
                   const float* __restrict__ bb, float* __restrict__ xout,
                   u16* __restrict__ xbout) {
  long t = (long)blockIdx.x * 4 + (threadIdx.x >> 6);
  int lane = threadIdx.x & 63;
  f32x4 e[3];
#pragma unroll
  for (int i = 0; i < 3; ++i) {
    long o4 = (t * 192 + i * 64 + lane) * 4;
    e[i] = *(const f32x4*)&xin[o4] + *(const f32x4*)&y0[o4] + *(const f32x4*)&y1[o4];
  }
  float sm = 0.f;
#pragma unroll
  for (int i = 0; i < 3; ++i) sm += e[i][0] + e[i][1] + e[i][2] + e[i][3];
  float mu = wave_sum(sm) * (1.0f / 768.0f);
  float vs = 0.f;
#pragma unroll
  for (int i = 0; i < 3; ++i)
#pragma unroll
    for (int c = 0; c < 4; ++c) { float d = e[i][c] - mu; vs += d * d; }
  float inv = rsqrtf(wave_sum(vs) * (1.0f / 768.0f) + 1e-12f);
#pragma unroll
  for (int i = 0; i < 3; ++i) {
    int c4 = i * 64 + lane;
    f32x4 gv = *(const f32x4*)&g[c4 * 4], bv = *(const f32x4*)&bb[c4 * 4];
    f32x4 o = (e[i] - mu) * inv * gv + bv;
    *(f32x4*)&xout[(t * 192 + c4) * 4] = o;
    u16x4 pk;
#pragma unroll
    for (int c = 0; c < 4; ++c) pk[c] = f2bf(o[c]);
    *(u16x4*)&xbout[(t * 192 + c4) * 4] = pk;
  }
}

// convert+transpose one layer's 6 weight matrices f32 (K x N) -> bf16 (N x K)
__global__ __launch_bounds__(256)
void convert_w_kernel(const float* __restrict__ wq, const float* __restrict__ wk,
                      const float* __restrict__ wv, const float* __restrict__ wo,
                      const float* __restrict__ wi, const float* __restrict__ wd,
                      u16* __restrict__ wqkvob, u16* __restrict__ wib,
                      u16* __restrict__ wdb) {
  __shared__ float tile[32][33];
  int t = blockIdx.x;
  const float* in;
  u16* outp;
  int Kd, Nd, kt, nt;
  if (t < 2304) {
    int m = t / 576, lt = t % 576;
    in = (m == 0) ? wq : (m == 1) ? wk : (m == 2) ? wv : wo;
    outp = wqkvob + (long)m * 589824;
    Kd = 768; Nd = 768; kt = lt / 24; nt = lt % 24;
  } else if (t < 4608) {
    int lt = t - 2304;
    in = wi; outp = wib; Kd = 768; Nd = 3072; kt = lt / 96; nt = lt % 96;
  } else {
    int lt = t - 4608;
    in = wd; outp = wdb; Kd = 3072; Nd = 768; kt = lt / 24; nt = lt % 24;
  }
  int tx = threadIdx.x, ty = threadIdx.y;
#pragma unroll
  for (int i = 0; i < 4; ++i)
    tile[ty + i * 8][tx] = in[(long)(kt * 32 + ty + i * 8) * Nd + nt * 32 + tx];
  __syncthreads();
  int t2 = ty * 32 + tx;
  if (t2 < 128) {  // 16B bf16 stores: thread -> (n row, 8-wide k chunk)
    int n = t2 >> 2, kcq = t2 & 3;
    u16x8 pk;
#pragma unroll
    for (int j = 0; j < 8; ++j) pk[j] = f2bf(tile[kcq * 8 + j][n]);
    *(u16x8*)&outp[(long)(nt * 32 + n) * Kd + kt * 32 + kcq * 8] = pk;
  }
}

// V (B,S,NH*64) bf16 -> Vt (B,NH,64,S) bf16
__global__ __launch_bounds__(256)
void transpose_v_kernel(const u16* __restrict__ vb, u16* __restrict__ vtb) {
  __shared__ u16 tile[32][33];
  int s0 = blockIdx.x * 32, d0 = blockIdx.y * 32;
  int b = blockIdx.z / 12, h = blockIdx.z % 12;
  int tx = threadIdx.x, ty = threadIdx.y;
#pragma unroll
  for (int i = 0; i < 4; ++i)
    tile[ty + i * 8][tx] = vb[(long)(b * 512 + s0 + ty + i * 8) * 768 + h * 64 + d0 + tx];
  __syncthreads();
#pragma unroll
  for (int i = 0; i < 4; ++i)
    vtb[(long)((b * 12 + h) * 64 + d0 + ty + i * 8) * 512 + s0 + tx] = tile[tx][ty + i * 8];
}

// C = A (M x lda bf16) * B^T (N x ldb bf16) + bias, 128x128 tile, BK=32,
// global_load_lds(16B) staging into unpadded swizzled LDS (reads 2-way = free).
// SPLITK: z in {0,1} takes K-halves [z*K, z*K+K); bias only on z==0.
// else: B += z*zoffB (QKV batching), bias_z. Out += z*zoffOut always.
template <int EPI, bool OBF16, bool SPLITK>
__global__ __launch_bounds__(256)
void gemm_kernel(const u16* __restrict__ A, const u16* __restrict__ Bmat,
                 long lda, long ldb, long zoffB,
                 const float* __restrict__ bias0, const float* __restrict__ bias1,
                 const float* __restrict__ bias2, void* __restrict__ Out, long zoffOut,
                 int M, int N, int K) {
  __shared__ __align__(16) u16 As[128 * 32];
  __shared__ __align__(16) u16 Bs[128 * 32];
  int z = blockIdx.z;
  long kOff = SPLITK ? (long)z * K : 0;
  const u16* Bz = Bmat + (SPLITK ? 0L : (long)z * zoffB);
  const float* bias = SPLITK ? bias0 : ((z == 0) ? bias0 : (z == 1) ? bias1 : bias2);
  bool addBias = (!SPLITK) || (z == 0);
  int m0 = blockIdx.x * 128, n0 = blockIdx.y * 128;
  int tid = threadIdx.x, w = tid >> 6, lane = tid & 63;
  int quad = lane >> 4, l16 = lane & 15;
  // staging map: lane -> row 32w+(lane>>2) (+16 instr1); global k-chunk XOR-swizzled
  int srow = 32 * w + (lane >> 2);
  int kc = (lane & 3) ^ ((lane >> 3) & 3);
  const u16* aG = A + (long)(m0 + srow) * lda + kOff + kc * 8;
  const u16* bG = Bz + (long)(n0 + srow) * ldb + kOff + kc * 8;
  u16* aL0 = &As[(32 * w) * 32];       // wave-uniform; DMA appends lane*16B
  u16* aL1 = &As[(32 * w + 16) * 32];
  u16* bL0 = &Bs[(32 * w) * 32];
  u16* bL1 = &Bs[(32 * w + 16) * 32];
  int slot = (quad ^ ((l16 >> 1) & 3)) * 8;  // u16 offset of this quad's frag in a row
  int wr = (w >> 1) * 64, wc = (w & 1) * 64;
  f32x4 acc[4][4] = {};
  for (int kk = 0; kk < K; kk += 32) {
    gload_lds16(aG + kk, aL0);
    gload_lds16(aG + 16 * lda + kk, aL1);
    gload_lds16(bG + kk, bL0);
    gload_lds16(bG + 16 * ldb + kk, bL1);
    __syncthreads();  // drains vmcnt(0) then barrier -> LDS tile visible
    bf16x8 af[4], bfv[4];
#pragma unroll
    for (int i = 0; i < 4; ++i) af[i] = *(const bf16x8*)&As[(wr + i * 16 + l16) * 32 + slot];
#pragma unroll
    for (int j = 0; j < 4; ++j) bfv[j] = *(const bf16x8*)&Bs[(wc + j * 16 + l16) * 32 + slot];
#pragma unroll
    for (int i = 0; i < 4; ++i)
#pragma unroll
      for (int j = 0; j < 4; ++j)
        acc[i][j] = __builtin_amdgcn_mfma_f32_16x16x32_bf16(af[i], bfv[j], acc[i][j], 0, 0, 0);
    __syncthreads();  // all reads done before next iter's DMA overwrites
  }
#pragma unroll
  for (int i = 0; i < 4; ++i) {
#pragma unroll
    for (int j = 0; j < 4; ++j) {
      int n = n0 + wc + j * 16 + l16;
      float bv = addBias ? bias[n] : 0.0f;
#pragma unroll
      for (int r = 0; r < 4; ++r) {  // C/D: row=(lane>>4)*4+reg, col=lane&15 (m89)
        int m = m0 + wr + i * 16 + quad * 4 + r;
        float v = acc[i][j][r] + bv;
        if (EPI == 2) v = v * 0.5f * (1.0f + erff(v * 0.70710678118654752f));
        long idx = (long)m * N + n;
        if (OBF16) ((u16*)Out)[(long)z * zoffOut + idx] = f2bf(v);
        else ((float*)Out)[(long)z * zoffOut + idx] = v;
      }
    }
  }
}

// fused flash attention: block = (b,h,64-q-rows); wave w owns 16 q rows.
__global__ __launch_bounds__(256)
void attn_kernel(const u16* __restrict__ qb, const u16* __restrict__ kb,
                 const u16* __restrict__ vtb, const float* __restrict__ keybias,
                 u16* __restrict__ ctxb) {
  __shared__ __align__(16) u16 Ks[64][72];   // [key][d]
  __shared__ __align__(16) u16 Vts[64][72];  // [d][key]
  __shared__ __align__(16) u16 Ps[4][16][72];
  int qt = blockIdx.x, h = blockIdx.y, b = blockIdx.z;
  int tid = threadIdx.x, w = tid >> 6, lane = tid & 63;
  int quad = lane >> 4, l16 = lane & 15;
  long qrow = (long)(b * 512 + qt * 64 + w * 16 + l16);
  bf16x8 qf0 = *(const bf16x8*)&qb[qrow * 768 + h * 64 + quad * 8];
  bf16x8 qf1 = *(const bf16x8*)&qb[qrow * 768 + h * 64 + 32 + quad * 8];
  f32x4 accO[4] = {};
  float mi[4], li[4];
#pragma unroll
  for (int r = 0; r < 4; ++r) { mi[r] = -1e30f; li[r] = 0.f; }
  for (int kt = 0; kt < 8; ++kt) {
    __syncthreads();
#pragma unroll
    for (int i = 0; i < 2; ++i) {
      int c = tid + i * 256;
      int row = c >> 3, dc = c & 7;
      *(uint4*)&Ks[row][dc * 8] =
          *(const uint4*)&kb[(long)(b * 512 + kt * 64 + row) * 768 + h * 64 + dc * 8];
      *(uint4*)&Vts[row][dc * 8] =
          *(const uint4*)&vtb[(long)((b * 12 + h) * 64 + row) * 512 + kt * 64 + dc * 8];
    }
    __syncthreads();
    f32x4 s[4] = {};
#pragma unroll
    for (int j = 0; j < 4; ++j) {
      bf16x8 kf0 = *(const bf16x8*)&Ks[j * 16 + l16][quad * 8];
      s[j] = __builtin_amdgcn_mfma_f32_16x16x32_bf16(qf0, kf0, s[j], 0, 0, 0);
      bf16x8 kf1 = *(const bf16x8*)&Ks[j * 16 + l16][32 + quad * 8];
      s[j] = __builtin_amdgcn_mfma_f32_16x16x32_bf16(qf1, kf1, s[j], 0, 0, 0);
    }
#pragma unroll
    for (int j = 0; j < 4; ++j) {
      float kbv = keybias[b * 512 + kt * 64 + j * 16 + l16];
#pragma unroll
      for (int r = 0; r < 4; ++r) s[j][r] = s[j][r] * 0.125f + kbv;
    }
#pragma unroll
    for (int r = 0; r < 4; ++r) {
      float mx = fmaxf(fmaxf(s[0][r], s[1][r]), fmaxf(s[2][r], s[3][r]));
      mx = fmaxf(mx, __shfl_xor(mx, 1));
      mx = fmaxf(mx, __shfl_xor(mx, 2));
      mx = fmaxf(mx, __shfl_xor(mx, 4));
      mx = fmaxf(mx, __shfl_xor(mx, 8));
      float mn = fmaxf(mi[r], mx);
      float alpha = __expf(mi[r] - mn);
      float ps = 0.f;
#pragma unroll
      for (int j = 0; j < 4; ++j) { s[j][r] = __expf(s[j][r] - mn); ps += s[j][r]; }
      ps += __shfl_xor(ps, 1);
      ps += __shfl_xor(ps, 2);
      ps += __shfl_xor(ps, 4);
      ps += __shfl_xor(ps, 8);
      li[r] = li[r] * alpha + ps;
      mi[r] = mn;
#pragma unroll
      for (int j = 0; j < 4; ++j) accO[j][r] *= alpha;
    }
#pragma unroll
    for (int j = 0; j < 4; ++j)
#pragma unroll
      for (int r = 0; r < 4; ++r)
        Ps[w][quad * 4 + r][j * 16 + l16] = f2bf(s[j][r]);
    __syncthreads();
#pragma unroll
    for (int kk = 0; kk < 2; ++kk) {
      bf16x8 pf = *(const bf16x8*)&Ps[w][l16][kk * 32 + quad * 8];
#pragma unroll
      for (int j = 0; j < 4; ++j) {
        bf16x8 vf = *(const bf16x8*)&Vts[j * 16 + l16][kk * 32 + quad * 8];
        accO[j] = __builtin_amdgcn_mfma_f32_16x16x32_bf16(pf, vf, accO[j], 0, 0, 0);
      }
    }
  }
#pragma unroll
  for (int j = 0; j < 4; ++j)
#pragma unroll
    for (int r = 0; r < 4; ++r) {
      float v = accO[j][r] / li[r];
      long row = (long)(b * 512 + qt * 64 + w * 16 + quad * 4 + r);
      ctxb[row * 768 + h * 64 + j * 16 + l16] = f2bf(v);
    }
}

__global__ __launch_bounds__(256)
void pooler_kernel(const float* __restrict__ xfin, const float* __restrict__ pw,
                   const float* __restrict__ pb, float* __restrict__ outp) {
  __shared__ float xr[768];
  int o = blockIdx.x * 256 + threadIdx.x;
  int b = blockIdx.y;
  for (int i = threadIdx.x; i < 768; i += 256) xr[i] = xfin[(long)b * 512 * 768 + i];
  __syncthreads();
  float acc = pb[o];
  for (int k = 0; k < 768; ++k) acc += xr[k] * pw[(long)k * 768 + o];
  outp[(long)b * 768 + o] = tanhf(acc);
}

extern "C" void kernel_launch(void* const* d_in, const int* in_sizes, int n_in,
                              void* d_out, int out_size, void* d_ws, size_t ws_size,
                              hipStream_t stream) {
  const int* ids = (const int*)d_in[0];
  const int* tts = (const int*)d_in[1];
  const float* amask = (const float*)d_in[2];
  const float* imp = (const float*)d_in[3];
  const float* noise = (const float*)d_in[4];
  const float* wemb = (const float*)d_in[5];
  const float* pemb = (const float*)d_in[6];
  const float* temb = (const float*)d_in[7];
  const float* elng = (const float*)d_in[8];
  const float* elnb = (const float*)d_in[9];
  const float* Wq = (const float*)d_in[10];
  const float* bq = (const float*)d_in[11];
  const float* Wk = (const float*)d_in[12];
  const float* bk = (const float*)d_in[13];
  const float* Wv = (const float*)d_in[14];
  const float* bv = (const float*)d_in[15];
  const float* Wo = (const float*)d_in[16];
  const float* bo = (const float*)d_in[17];
  const float* ln1g = (const float*)d_in[18];
  const float* ln1b = (const float*)d_in[19];
  const float* Wi = (const float*)d_in[20];
  const float* bi = (const float*)d_in[21];
  const float* Wd = (const float*)d_in[22];
  const float* bd = (const float*)d_in[23];
  const float* ln2g = (const float*)d_in[24];
  const float* ln2b = (const float*)d_in[25];
  const float* poolw = (const float*)d_in[26];
  const float* poolb = (const float*)d_in[27];
  float* out = (float*)d_out;

  const long T = 8192;  // B*S
  char* p = (char*)d_ws;
  auto carve = [&](size_t bytes) -> void* {
    void* r = (void*)p;
    p += (bytes + 255) & ~(size_t)255;
    return r;
  };
  float* x = (float*)carve(T * 768 * 4);
  float* y = (float*)carve(T * 768 * 4);
  u16* xb = (u16*)carve(T * 768 * 2);
  u16* qkvb = (u16*)carve(3 * T * 768 * 2);
  u16* vtb = (u16*)carve(T * 768 * 2);
  u16* ctxb = (u16*)carve(T * 768 * 2);
  u16* hb = (u16*)carve(T * 3072 * 2);
  u16* wqkvob = (u16*)carve(4L * 589824 * 2);
  u16* wib = (u16*)carve(2359296L * 2);
  u16* wdb = (u16*)carve(2359296L * 2);
  float* kbias = (float*)carve(T * 4);
  if ((size_t)(p - (char*)d_ws) > ws_size) return;  // ws too small: fail visibly

  // split-K partial #2 lands in qkvb (free between attention and next-layer QKV)
  float* y1 = (float*)qkvb;
  long zoffO = (long)(y1 - y);  // element offset from y to y1

  keybias_kernel<<<32, 256, 0, stream>>>(amask, kbias, (int)T);
  embed_ln_kernel<<<(int)(T / 4), 256, 0, stream>>>(ids, tts, imp, noise, wemb, pemb,
                                                    temb, elng, elnb, x, xb);

  for (int l = 0; l < 12; ++l) {
    convert_w_kernel<<<6912, dim3(32, 8), 0, stream>>>(
        Wq + (long)l * 589824, Wk + (long)l * 589824, Wv + (long)l * 589824,
        Wo + (long)l * 589824, Wi + (long)l * 2359296, Wd + (long)l * 2359296,
        wqkvob, wib, wdb);
    // QKV batched over z
    gemm_kernel<1, true, false><<<dim3(64, 6, 3), 256, 0, stream>>>(
        xb, wqkvob, 768, 768, 589824L, bq + (long)l * 768, bk + (long)l * 768,
        bv + (long)l * 768, (void*)qkvb, T * 768, 8192, 768, 768);
    transpose_v_kernel<<<dim3(16, 2, 192), dim3(32, 8), 0, stream>>>(qkvb + 2 * T * 768, vtb);
    attn_kernel<<<dim3(8, 12, 16), 256, 0, stream>>>(qkvb, qkvb + T * 768, vtb, kbias, ctxb);
    // O-proj: split-K=2 (768 blocks, balanced); z=1 partial -> y1 (=qkvb, now dead)
    gemm_kernel<1, false, true><<<dim3(64, 6, 2), 256, 0, stream>>>(
        ctxb, wqkvob + 3L * 589824, 768, 768, 0L, bo + (long)l * 768, bo + (long)l * 768,
        bo + (long)l * 768, (void*)y, zoffO, 8192, 768, 384);
    ln_res_kernel<<<(int)(T / 4), 256, 0, stream>>>(x, y, y1, ln1g + (long)l * 768,
                                                    ln1b + (long)l * 768, x, xb);
    gemm_kernel<2, true, false><<<dim3(64, 24, 1), 256, 0, stream>>>(
        xb, wib, 768, 768, 0L, bi + (long)l * 3072, bi + (long)l * 3072,
        bi + (long)l * 3072, (void*)hb, 0L, 8192, 3072, 768);
    // FF2: split-K=2 over K=3072
    gemm_kernel<1, false, true><<<dim3(64, 6, 2), 256, 0, stream>>>(
        hb, wdb, 3072, 3072, 0L, bd + (long)l * 768, bd + (long)l * 768,
        bd + (long)l * 768, (void*)y, zoffO, 8192, 768, 1536);
    float* xo = (l == 11) ? out : x;
    ln_res_kernel<<<(int)(T / 4), 256, 0, stream>>>(x, y, y1, ln2g + (long)l * 768,
                                                    ln2b + (long)l * 768, xo, xb);
  }
  pooler_kernel<<<dim3(3, 16), 256, 0, stream>>>(out, poolw, poolb, out + T * 768);
}